// Round 2
// baseline (157.161 us; speedup 1.0000x reference)
//
#include <hip/hip_runtime.h>
#include <hip/hip_bf16.h>

#define B_ 8
#define S_ 256
#define L_ 64
#define E_ 128

// Kernel A: one 64-lane wave per (b,l).
// raw[s] = harmony[b,l] . note[b,s]; m = max_s raw[s]*scale;
// e[s] = exp(raw[s]*scale - m); stores float2(e, e*raw) transposed as
// ws[b][s][l] so kernel B (lane = l) gets coalesced loads.
// Using the per-row max instead of the reference's per-start suffix max is
// exact for the final ratio c2/c1 (the max cancels), and cannot underflow:
// scaled logits span ~[-5,5], so e >= exp(-10).
__global__ __launch_bounds__(64) void prep_kernel(const float* __restrict__ note,
                                                  const float* __restrict__ harmony,
                                                  float2* __restrict__ ws) {
    const int b = blockIdx.x / L_;
    const int l = blockIdx.x % L_;
    const int lane = threadIdx.x;

    __shared__ float h[E_];
    const float* hp = harmony + (size_t)(b * L_ + l) * E_;
    h[lane]      = hp[lane];
    h[lane + 64] = hp[lane + 64];
    __syncthreads();

    float raw[4];
#pragma unroll
    for (int k = 0; k < 4; ++k) {
        const int s = lane + 64 * k;
        const float4* nv = reinterpret_cast<const float4*>(note + (size_t)(b * S_ + s) * E_);
        float acc = 0.f;
#pragma unroll
        for (int e = 0; e < E_ / 4; ++e) {
            float4 v = nv[e];
            acc += h[4 * e + 0] * v.x + h[4 * e + 1] * v.y +
                   h[4 * e + 2] * v.z + h[4 * e + 3] * v.w;
        }
        raw[k] = acc;
    }

    const float scale = 0.088388347648318447f;  // 1/sqrt(128)

    float m = fmaxf(fmaxf(raw[0], raw[1]), fmaxf(raw[2], raw[3]));
#pragma unroll
    for (int off = 1; off < 64; off <<= 1)
        m = fmaxf(m, __shfl_xor(m, off, 64));
    m *= scale;

#pragma unroll
    for (int k = 0; k < 4; ++k) {
        const int s = lane + 64 * k;
        float e_ = __expf(raw[k] * scale - m);
        ws[(size_t)(b * S_ + s) * L_ + l] = make_float2(e_, e_ * raw[k]);
    }
}

// Kernel B: one 64-lane wave per (b, start); lane = l.
// out[b][start][end][l] = (sum_{s=start..end} e*raw) / (sum_{s=start..end} e),
// 0 for end < start. All-positive serial accumulation: no cancellation.
__global__ __launch_bounds__(64) void score_kernel(const float2* __restrict__ ws,
                                                   float* __restrict__ out) {
    const int b     = blockIdx.x >> 8;
    const int start = blockIdx.x & 255;
    const int l     = threadIdx.x;

    float* orow = out + ((size_t)(b * S_ + start) * S_) * L_ + l;

    // end < start: zeros (output buffer is poisoned before each launch).
    for (int end = 0; end < start; ++end)
        orow[(size_t)end * L_] = 0.f;

    const float2* w = ws + (size_t)(b * S_) * L_ + l;
    float c1 = 0.f, c2 = 0.f;
#pragma unroll 4
    for (int end = start; end < S_; ++end) {
        float2 v = w[(size_t)end * L_];
        c1 += v.x;
        c2 += v.y;
        orow[(size_t)end * L_] = c2 * __builtin_amdgcn_rcpf(c1);
    }
}

extern "C" void kernel_launch(void* const* d_in, const int* in_sizes, int n_in,
                              void* d_out, int out_size, void* d_ws, size_t ws_size,
                              hipStream_t stream) {
    const float* note    = (const float*)d_in[0];
    const float* harmony = (const float*)d_in[1];
    float2* ws           = (float2*)d_ws;  // B*S*L float2 = 1 MiB
    float* out           = (float*)d_out;  // [B, S_start, S_end, L] f32

    hipLaunchKernelGGL(prep_kernel, dim3(B_ * L_), dim3(64), 0, stream,
                       note, harmony, ws);
    hipLaunchKernelGGL(score_kernel, dim3(B_ * S_), dim3(64), 0, stream,
                       ws, out);
}